// Round 1
// baseline (385.727 us; speedup 1.0000x reference)
//
#include <hip/hip_runtime.h>
#include <stdint.h>

// Problem constants (from reference): B=32, S=2048, K=512, V=512, H=256
#define Bb 32
#define Ss 2048
#define Kk 512
#define Vv 512
#define Hh 256

#define OUTP (Bb * Vv) // offset of p within d_out (out is [1,B,V] = 16384 floats)

// ws layout (bytes):
//   [0,       32768)   hq[B][H] fp32 (= q@Wq^T + bq + bk  -- bk folded in)
//   [32768,  294912)   Wk bf16, tiled [8 stages][256 h][64 k]
//   [294912, 557056)   logits[B][S] fp32
#define WS_HQ 0
#define WS_WKB 32768
#define WS_LOGIT 294912

typedef float floatx4 __attribute__((ext_vector_type(4)));
typedef __bf16 bf16x8 __attribute__((ext_vector_type(8)));

__device__ __forceinline__ uint32_t bfround(float f) {
  // RNE float -> bf16 (as uint16 in low bits)
  uint32_t u = __float_as_uint(f);
  return (u + 0x7fffu + ((u >> 16) & 1u)) >> 16;
}
__device__ __forceinline__ uint32_t packbf(float lo, float hi) {
  return bfround(lo) | (bfround(hi) << 16);
}

// ---------------------------------------------------------------------------
// Kernel 1a: hq[b][h] = sum_k q[b,k]*Wq[h,k] + bq[h] + bk[h]
// (bk folded here since h = tanh(h_k + bk + h_q))
__global__ void prep_hq(const float* __restrict__ q, const float* __restrict__ Wq,
                        const float* __restrict__ bq, const float* __restrict__ bk,
                        float* __restrict__ hq) {
  const int b = blockIdx.x;   // 32
  const int h = threadIdx.x;  // 256
  const float4* qp = (const float4*)(q + b * Kk);
  const float4* wp = (const float4*)(Wq + h * Kk);
  float acc = 0.f;
  for (int i = 0; i < Kk / 4; ++i) {
    float4 qa = qp[i], wa = wp[i];
    acc = fmaf(qa.x, wa.x, acc);
    acc = fmaf(qa.y, wa.y, acc);
    acc = fmaf(qa.z, wa.z, acc);
    acc = fmaf(qa.w, wa.w, acc);
  }
  hq[b * Hh + h] = acc + bq[h] + bk[h];
}

// ---------------------------------------------------------------------------
// Kernel 1b: convert Wk [H][K] fp32 -> bf16, tiled [stage=k/64][h][k%64]
// so main-kernel staging reads are contiguous per stage.
__global__ void prep_wk(const float* __restrict__ Wk, uint16_t* __restrict__ wkb) {
  const int i = (blockIdx.x * 256 + threadIdx.x) * 4; // grid 128 blocks: 131072 elems
  float4 w = *(const float4*)(Wk + i);
  const int h = i >> 9;
  const int k = i & 511;
  const int stage = k >> 6;
  const int kin = k & 63;
  uint2 pk;
  pk.x = packbf(w.x, w.y);
  pk.y = packbf(w.z, w.w);
  *(uint2*)(wkb + stage * (Hh * 64) + h * 64 + kin) = pk;
}

// ---------------------------------------------------------------------------
// Kernel 2: per (b, s-tile of 64): logit[s] = sum_h tanh(k_row@Wk^T + hq) * Wo
// BM=64, BN=256 (all of H -> k read exactly once), BK=64, 256 thr = 4 waves,
// each wave a 64x64 subtile via 4x4 mfma_f32_16x16x32_bf16.
#define BM 64
#define LDP 72 // padded LDS row stride (144 B -> 4-bank rotation, free 2-way)

__global__ __launch_bounds__(256, 2) void fused_gemm_tanh_logit(
    const float* __restrict__ kin, const uint16_t* __restrict__ wkb,
    const float* __restrict__ hq, const float* __restrict__ Wo,
    float* __restrict__ logits) {
  __shared__ uint16_t lA[BM][LDP];
  __shared__ uint16_t lB[Hh][LDP];
  __shared__ float lpart[4][BM];

  const int tid = threadIdx.x;
  const int b = blockIdx.y;
  const int s0 = blockIdx.x * BM;
  const int wid = tid >> 6;
  const int lane = tid & 63;
  const int l15 = lane & 15;
  const int lg = lane >> 4;

  // per-lane epilogue params: this lane's 4 output columns (h indices)
  float hqv[4], wov[4];
#pragma unroll
  for (int ni = 0; ni < 4; ++ni) {
    const int n = wid * 64 + ni * 16 + l15;
    hqv[ni] = hq[b * Hh + n];
    wov[ni] = Wo[n];
  }

  floatx4 acc[4][4];
#pragma unroll
  for (int mi = 0; mi < 4; ++mi)
#pragma unroll
    for (int ni = 0; ni < 4; ++ni)
      acc[mi][ni] = (floatx4){0.f, 0.f, 0.f, 0.f};

  const int arow = tid >> 4;       // 0..15 (A row within 16-row chunk)
  const int acol = (tid & 15) * 4; // A col in floats (0..60)
  const int bcol = (tid & 7) * 8;  // B col in bf16

  for (int ks = 0; ks < 8; ++ks) {
    // --- global loads (before barrier: overlap with previous stage compute)
    float4 av[4];
#pragma unroll
    for (int it = 0; it < 4; ++it) {
      const int row = it * 16 + arow;
      av[it] = *(const float4*)(kin + ((s0 + row) * Bb + b) * Kk + ks * 64 + acol);
    }
    uint4 bv[8];
    const uint4* bsrc = (const uint4*)(wkb + ks * (Hh * 64));
#pragma unroll
    for (int it = 0; it < 8; ++it) bv[it] = bsrc[it * 256 + tid];

    __syncthreads(); // previous stage's frag reads done
#pragma unroll
    for (int it = 0; it < 4; ++it) {
      const int row = it * 16 + arow;
      uint2 pk;
      pk.x = packbf(av[it].x, av[it].y);
      pk.y = packbf(av[it].z, av[it].w);
      *(uint2*)&lA[row][acol] = pk;
    }
#pragma unroll
    for (int it = 0; it < 8; ++it) {
      const int g = it * 256 + tid;
      *(uint4*)&lB[g >> 3][bcol] = bv[it];
    }
    __syncthreads();

#pragma unroll
    for (int kk = 0; kk < 2; ++kk) {
      bf16x8 af[4], bfr[4];
#pragma unroll
      for (int mi = 0; mi < 4; ++mi)
        af[mi] = *(const bf16x8*)&lA[mi * 16 + l15][kk * 32 + lg * 8];
#pragma unroll
      for (int ni = 0; ni < 4; ++ni)
        bfr[ni] = *(const bf16x8*)&lB[wid * 64 + ni * 16 + l15][kk * 32 + lg * 8];
#pragma unroll
      for (int mi = 0; mi < 4; ++mi)
#pragma unroll
        for (int ni = 0; ni < 4; ++ni)
          acc[mi][ni] =
              __builtin_amdgcn_mfma_f32_16x16x32_bf16(af[mi], bfr[ni], acc[mi][ni], 0, 0, 0);
    }
  }

  // --- epilogue: tanh + dot with Wo, reduce across the 16 col-lanes
  // C/D layout (m89-verified): col = lane&15, row = (lane>>4)*4 + reg
#pragma unroll
  for (int mi = 0; mi < 4; ++mi) {
#pragma unroll
    for (int r = 0; r < 4; ++r) {
      float sum = 0.f;
#pragma unroll
      for (int ni = 0; ni < 4; ++ni) {
        const float x = acc[mi][ni][r] + hqv[ni];
        const float e = __expf(2.f * x);
        // tanh(x) = 1 - 2/(e^{2x}+1); e->inf gives 1, e->0 gives -1 (no NaN)
        const float th = 1.f - 2.f * __builtin_amdgcn_rcpf(e + 1.f);
        sum = fmaf(th, wov[ni], sum);
      }
      sum += __shfl_xor(sum, 1, 64);
      sum += __shfl_xor(sum, 2, 64);
      sum += __shfl_xor(sum, 4, 64);
      sum += __shfl_xor(sum, 8, 64);
      if (l15 == 0) lpart[wid][mi * 16 + lg * 4 + r] = sum;
    }
  }
  __syncthreads();
  if (tid < BM) {
    const float lv = lpart[0][tid] + lpart[1][tid] + lpart[2][tid] + lpart[3][tid];
    logits[b * Ss + s0 + tid] = lv; // bo omitted: cancels in softmax
  }
}

// ---------------------------------------------------------------------------
// Kernel 3: per-b softmax over S=2048 -> p into d_out; also zero out-section.
__global__ void softmax_zero(const float* __restrict__ logits, float* __restrict__ dout) {
  const int b = blockIdx.x;
  const int t = threadIdx.x; // 256
  const int wid = t >> 6, lane = t & 63;
  __shared__ float red[4];
  const float4* lp = (const float4*)(logits + b * Ss);
  const float4 x0 = lp[t * 2], x1 = lp[t * 2 + 1];
  float mx = fmaxf(fmaxf(fmaxf(x0.x, x0.y), fmaxf(x0.z, x0.w)),
                   fmaxf(fmaxf(x1.x, x1.y), fmaxf(x1.z, x1.w)));
#pragma unroll
  for (int off = 1; off < 64; off <<= 1) mx = fmaxf(mx, __shfl_xor(mx, off, 64));
  if (lane == 0) red[wid] = mx;
  __syncthreads();
  mx = fmaxf(fmaxf(red[0], red[1]), fmaxf(red[2], red[3]));
  __syncthreads();
  float e[8];
  e[0] = __expf(x0.x - mx); e[1] = __expf(x0.y - mx);
  e[2] = __expf(x0.z - mx); e[3] = __expf(x0.w - mx);
  e[4] = __expf(x1.x - mx); e[5] = __expf(x1.y - mx);
  e[6] = __expf(x1.z - mx); e[7] = __expf(x1.w - mx);
  float s = ((e[0] + e[1]) + (e[2] + e[3])) + ((e[4] + e[5]) + (e[6] + e[7]));
#pragma unroll
  for (int off = 1; off < 64; off <<= 1) s += __shfl_xor(s, off, 64);
  if (lane == 0) red[wid] = s;
  __syncthreads();
  s = (red[0] + red[1]) + (red[2] + red[3]);
  const float inv = 1.f / s;
  float4 p0, p1;
  p0.x = e[0] * inv; p0.y = e[1] * inv; p0.z = e[2] * inv; p0.w = e[3] * inv;
  p1.x = e[4] * inv; p1.y = e[5] * inv; p1.z = e[6] * inv; p1.w = e[7] * inv;
  float4* pout = (float4*)(dout + OUTP + b * Ss);
  pout[t * 2] = p0;
  pout[t * 2 + 1] = p1;
  // zero out-section (atomic accumulation target in kernel 4)
  dout[b * Vv + t] = 0.f;
  dout[b * Vv + 256 + t] = 0.f;
}

// ---------------------------------------------------------------------------
// Kernel 4: out[b][vi] = sum_s p[b][s] * v[s][b][vi].  Streams v (128 MB).
__global__ __launch_bounds__(256) void weighted_vsum(const float* __restrict__ v,
                                                     float* __restrict__ dout) {
  const int sc = blockIdx.x; // 16 S-chunks of 128
  const int b = blockIdx.y;  // 32
  const int t = threadIdx.x; // 256, each handles 2 v-cols
  __shared__ float lp[128];
  const float* p = dout + OUTP;
  if (t < 128) lp[t] = p[b * Ss + sc * 128 + t];
  __syncthreads();
  const float2* vp = (const float2*)v;
  float ax = 0.f, ay = 0.f;
  const int sbase = sc * 128;
#pragma unroll 4
  for (int s = 0; s < 128; ++s) {
    const float2 vv = vp[((sbase + s) * Bb + b) * (Vv / 2) + t];
    const float pw = lp[s];
    ax = fmaf(pw, vv.x, ax);
    ay = fmaf(pw, vv.y, ay);
  }
  atomicAdd(dout + b * Vv + 2 * t, ax);
  atomicAdd(dout + b * Vv + 2 * t + 1, ay);
}

// ---------------------------------------------------------------------------
extern "C" void kernel_launch(void* const* d_in, const int* in_sizes, int n_in,
                              void* d_out, int out_size, void* d_ws, size_t ws_size,
                              hipStream_t stream) {
  const float* q  = (const float*)d_in[0];
  const float* k  = (const float*)d_in[1];
  const float* v  = (const float*)d_in[2];
  const float* Wk = (const float*)d_in[3];
  const float* bk = (const float*)d_in[4];
  const float* Wq = (const float*)d_in[5];
  const float* bq = (const float*)d_in[6];
  const float* Wo = (const float*)d_in[7];
  // bo (d_in[8]) cancels in softmax and is not part of any output -> unused.

  float* out = (float*)d_out;
  char* ws = (char*)d_ws;
  float* hq = (float*)(ws + WS_HQ);
  uint16_t* wkb = (uint16_t*)(ws + WS_WKB);
  float* logits = (float*)(ws + WS_LOGIT);

  prep_hq<<<dim3(Bb), dim3(256), 0, stream>>>(q, Wq, bq, bk, hq);
  prep_wk<<<dim3(128), dim3(256), 0, stream>>>(Wk, wkb);
  fused_gemm_tanh_logit<<<dim3(Ss / BM, Bb), dim3(256), 0, stream>>>(k, wkb, hq, Wo, logits);
  softmax_zero<<<dim3(Bb), dim3(256), 0, stream>>>(logits, out);
  weighted_vsum<<<dim3(16, Bb), dim3(256), 0, stream>>>(v, out);
}

// Round 2
// 330.945 us; speedup vs baseline: 1.1655x; 1.1655x over previous
//
#include <hip/hip_runtime.h>
#include <stdint.h>

// Problem constants: B=32, S=2048, K=512, V=512, H=256
#define Bb 32
#define Ss 2048
#define Kk 512
#define Vv 512
#define Hh 256

#define OUTP (Bb * Vv) // offset of p within d_out (out [1,B,V] then p [B,S])

// ws layout (bytes):
//   [0,       32768)   hq[B][H] fp32 (= q@Wq^T + bq + bk)
//   [32768,  294912)   Wk bf16, frag-major: [stage][ (kk*4+lg) ][n][8]
//   [294912, 557056)   logits[B][S] fp32
#define WS_HQ 0
#define WS_WKB 32768
#define WS_LOGIT 294912

typedef float floatx4 __attribute__((ext_vector_type(4)));
typedef __bf16 bf16x8 __attribute__((ext_vector_type(8)));

__device__ __forceinline__ uint32_t bfround(float f) {
  uint32_t u = __float_as_uint(f);
  return (u + 0x7fffu + ((u >> 16) & 1u)) >> 16;
}
__device__ __forceinline__ uint32_t packbf(float lo, float hi) {
  return bfround(lo) | (bfround(hi) << 16);
}

// async global->LDS, 16B per lane; lds dest is wave-uniform base + lane*16
__device__ __forceinline__ void gload_lds16(const uint16_t* g, uint16_t* l) {
  __builtin_amdgcn_global_load_lds((const __attribute__((address_space(1))) void*)g,
                                   (__attribute__((address_space(3))) void*)l, 16, 0, 0);
}

// ---------------------------------------------------------------------------
// prep (merged): blocks [0,128): retile Wk fp32 -> bf16 frag-major.
//                blocks [128,384): hq[b][h] = q[b]·Wq[h] + bq[h] + bk[h]
__global__ void prep(const float* __restrict__ q, const float* __restrict__ Wq,
                     const float* __restrict__ bq, const float* __restrict__ bk,
                     const float* __restrict__ Wk, uint16_t* __restrict__ wkb,
                     float* __restrict__ hq) {
  __shared__ float red[256];
  const int bx = blockIdx.x;
  const int t = threadIdx.x;
  if (bx < 128) {
    const int i = (bx * 256 + t) * 4; // 4 consecutive k of one h row
    float4 w = *(const float4*)(Wk + i);
    const int h = i >> 9;
    const int k = i & 511;
    const int stage = k >> 6;
    const int kin = k & 63;
    const int grp = kin >> 3; // kk*4+lg (0..7)
    const int j = kin & 7;    // 0 or 4 here
    uint2 pk;
    pk.x = packbf(w.x, w.y);
    pk.y = packbf(w.z, w.w);
    *(uint2*)(wkb + stage * 16384 + (grp * 256 + h) * 8 + j) = pk;
  } else {
    const int idx = bx - 128; // 0..255
    const int b = idx >> 3;
    const int hc = idx & 7;
    const int h_in = t & 31;
    const int kp = t >> 5; // 8-way K split
    const int h = hc * 32 + h_in;
    const float4* qp = (const float4*)(q + b * Kk + kp * 64);
    const float4* wp = (const float4*)(Wq + h * Kk + kp * 64);
    float acc = 0.f;
#pragma unroll
    for (int i = 0; i < 16; ++i) {
      float4 qa = qp[i], wa = wp[i];
      acc = fmaf(qa.x, wa.x, acc);
      acc = fmaf(qa.y, wa.y, acc);
      acc = fmaf(qa.z, wa.z, acc);
      acc = fmaf(qa.w, wa.w, acc);
    }
    red[t] = acc;
    __syncthreads();
    if (t < 32) {
      float s = 0.f;
#pragma unroll
      for (int kp2 = 0; kp2 < 8; ++kp2) s += red[kp2 * 32 + t];
      const int hh = hc * 32 + t;
      hq[b * Hh + hh] = s + bq[hh] + bk[hh];
    }
  }
}

// ---------------------------------------------------------------------------
// Main GEMM+tanh+logit. BM=64 rows of k, BN=256 (full H), BK=64, 8 stages.
// A staged via reg->cvt->ds_write (frag-major), B via global_load_lds (already
// frag-major in ws). m97 2-barrier loop, no register liveness across barriers
// except the 16-VGPR A prefetch issued after the drain barrier.
__global__ __launch_bounds__(256, 3) void fused_gemm_tanh_logit(
    const float* __restrict__ kin, const uint16_t* __restrict__ wkb,
    const float* __restrict__ hq, const float* __restrict__ Wo,
    float* __restrict__ logits) {
  __shared__ __align__(16) uint16_t lA[64 * 64];  // ((kk*4+lg)*64 + m)*8 + j
  __shared__ __align__(16) uint16_t lB[256 * 64]; // ((kk*4+lg)*256 + n)*8 + j
  __shared__ float lpart[4][64];

  const int tid = threadIdx.x;
  const int b = blockIdx.y;
  const int s0 = blockIdx.x * 64;
  const int wid = tid >> 6;
  const int lane = tid & 63;
  const int l15 = lane & 15;
  const int lg = lane >> 4;

  float hqv[4], wov[4];
#pragma unroll
  for (int ni = 0; ni < 4; ++ni) {
    const int n = wid * 64 + ni * 16 + l15;
    hqv[ni] = hq[b * Hh + n];
    wov[ni] = Wo[n];
  }

  floatx4 acc[4][4];
#pragma unroll
  for (int mi = 0; mi < 4; ++mi)
#pragma unroll
    for (int ni = 0; ni < 4; ++ni) acc[mi][ni] = (floatx4){0.f, 0.f, 0.f, 0.f};

  // A assignment: thread t -> k-group kg (8 floats wide), rows mrow, mrow+1
  const int kg = tid >> 5;
  const int mrow = (tid & 31) * 2;
  const float* a0 = kin + ((size_t)(s0 + mrow) * Bb + b) * Kk + kg * 8;
  const float* a1 = a0 + (size_t)Bb * Kk;

  float4 av0, av1, av2, av3;
  av0 = *(const float4*)(a0);
  av1 = *(const float4*)(a0 + 4);
  av2 = *(const float4*)(a1);
  av3 = *(const float4*)(a1 + 4);

  const uint16_t* bstage = wkb + (wid * 8) * 512 + lane * 8;
  uint16_t* bdst0 = &lB[(wid * 8) * 512];

  for (int ks = 0; ks < 8; ++ks) {
    __syncthreads(); // previous stage's LDS reads complete
    // stage A: cvt regs -> frag-major LDS
    uint4 w0, w1;
    w0.x = packbf(av0.x, av0.y);
    w0.y = packbf(av0.z, av0.w);
    w0.z = packbf(av1.x, av1.y);
    w0.w = packbf(av1.z, av1.w);
    w1.x = packbf(av2.x, av2.y);
    w1.y = packbf(av2.z, av2.w);
    w1.z = packbf(av3.x, av3.y);
    w1.w = packbf(av3.z, av3.w);
    *(uint4*)&lA[(kg * 64 + mrow) * 8] = w0;
    *(uint4*)&lA[(kg * 64 + mrow + 1) * 8] = w1;
    // stage B: async, zero registers
    const uint16_t* bsrc = bstage + ks * 16384;
#pragma unroll
    for (int it = 0; it < 8; ++it) gload_lds16(bsrc + it * 512, bdst0 + it * 512);
    __syncthreads(); // drains vmcnt (global_load_lds) + lgkm (ds_write)
    // prefetch A for next stage; waits overlap the compute below
    if (ks < 7) {
      av0 = *(const float4*)(a0 + (ks + 1) * 64);
      av1 = *(const float4*)(a0 + (ks + 1) * 64 + 4);
      av2 = *(const float4*)(a1 + (ks + 1) * 64);
      av3 = *(const float4*)(a1 + (ks + 1) * 64 + 4);
    }
#pragma unroll
    for (int kk = 0; kk < 2; ++kk) {
      bf16x8 af[4], bfr[4];
#pragma unroll
      for (int mi = 0; mi < 4; ++mi)
        af[mi] = *(const bf16x8*)&lA[((kk * 4 + lg) * 64 + mi * 16 + l15) * 8];
#pragma unroll
      for (int ni = 0; ni < 4; ++ni)
        bfr[ni] = *(const bf16x8*)&lB[((kk * 4 + lg) * 256 + wid * 64 + ni * 16 + l15) * 8];
#pragma unroll
      for (int mi = 0; mi < 4; ++mi)
#pragma unroll
        for (int ni = 0; ni < 4; ++ni)
          acc[mi][ni] =
              __builtin_amdgcn_mfma_f32_16x16x32_bf16(af[mi], bfr[ni], acc[mi][ni], 0, 0, 0);
    }
  }

  // epilogue: tanh + dot with Wo; C/D layout: col = lane&15, row = lg*4 + reg
#pragma unroll
  for (int mi = 0; mi < 4; ++mi) {
#pragma unroll
    for (int r = 0; r < 4; ++r) {
      float sum = 0.f;
#pragma unroll
      for (int ni = 0; ni < 4; ++ni) {
        const float x = acc[mi][ni][r] + hqv[ni];
        const float e = __expf(2.f * x);
        const float th = 1.f - 2.f * __builtin_amdgcn_rcpf(e + 1.f);
        sum = fmaf(th, wov[ni], sum);
      }
      sum += __shfl_xor(sum, 1, 64);
      sum += __shfl_xor(sum, 2, 64);
      sum += __shfl_xor(sum, 4, 64);
      sum += __shfl_xor(sum, 8, 64);
      if (l15 == 0) lpart[wid][mi * 16 + lg * 4 + r] = sum;
    }
  }
  __syncthreads();
  if (tid < 64) {
    const float lv = lpart[0][tid] + lpart[1][tid] + lpart[2][tid] + lpart[3][tid];
    logits[b * Ss + s0 + tid] = lv; // bo omitted: cancels in softmax
  }
}

// ---------------------------------------------------------------------------
// softmax over S per b -> p into d_out; zero out-section for vsum atomics.
__global__ void softmax_zero(const float* __restrict__ logits, float* __restrict__ dout) {
  const int b = blockIdx.x;
  const int t = threadIdx.x; // 256
  const int wid = t >> 6, lane = t & 63;
  __shared__ float red[4];
  const float4* lp = (const float4*)(logits + b * Ss);
  const float4 x0 = lp[t * 2], x1 = lp[t * 2 + 1];
  float mx = fmaxf(fmaxf(fmaxf(x0.x, x0.y), fmaxf(x0.z, x0.w)),
                   fmaxf(fmaxf(x1.x, x1.y), fmaxf(x1.z, x1.w)));
#pragma unroll
  for (int off = 1; off < 64; off <<= 1) mx = fmaxf(mx, __shfl_xor(mx, off, 64));
  if (lane == 0) red[wid] = mx;
  __syncthreads();
  mx = fmaxf(fmaxf(red[0], red[1]), fmaxf(red[2], red[3]));
  __syncthreads();
  float e[8];
  e[0] = __expf(x0.x - mx); e[1] = __expf(x0.y - mx);
  e[2] = __expf(x0.z - mx); e[3] = __expf(x0.w - mx);
  e[4] = __expf(x1.x - mx); e[5] = __expf(x1.y - mx);
  e[6] = __expf(x1.z - mx); e[7] = __expf(x1.w - mx);
  float s = ((e[0] + e[1]) + (e[2] + e[3])) + ((e[4] + e[5]) + (e[6] + e[7]));
#pragma unroll
  for (int off = 1; off < 64; off <<= 1) s += __shfl_xor(s, off, 64);
  if (lane == 0) red[wid] = s;
  __syncthreads();
  s = (red[0] + red[1]) + (red[2] + red[3]);
  const float inv = 1.f / s;
  float4 p0, p1;
  p0.x = e[0] * inv; p0.y = e[1] * inv; p0.z = e[2] * inv; p0.w = e[3] * inv;
  p1.x = e[4] * inv; p1.y = e[5] * inv; p1.z = e[6] * inv; p1.w = e[7] * inv;
  float4* pout = (float4*)(dout + OUTP + b * Ss);
  pout[t * 2] = p0;
  pout[t * 2 + 1] = p1;
  dout[b * Vv + t] = 0.f;
  dout[b * Vv + 256 + t] = 0.f;
}

// ---------------------------------------------------------------------------
// out[b][:] += sum_s p[b][s] * v[s][b][:].  float4 coalesced streaming of v.
__global__ __launch_bounds__(256) void weighted_vsum(const float* __restrict__ v,
                                                     float* __restrict__ dout) {
  const int sc = blockIdx.x; // 16 S-chunks of 128
  const int b = blockIdx.y;  // 32
  const int t = threadIdx.x;
  __shared__ float lp[128];
  if (t < 128) lp[t] = dout[OUTP + b * Ss + sc * 128 + t];
  __syncthreads();
  const int c4 = t & 127; // float4 column
  const int sh = t >> 7;  // 0/1: s parity
  float4 acc = {0.f, 0.f, 0.f, 0.f};
#pragma unroll 8
  for (int i = 0; i < 64; ++i) {
    const int sl = sh + 2 * i;
    const int s = sc * 128 + sl;
    const float4 vv = *(const float4*)(v + ((size_t)s * Bb + b) * Vv + c4 * 4);
    const float pw = lp[sl];
    acc.x = fmaf(pw, vv.x, acc.x);
    acc.y = fmaf(pw, vv.y, acc.y);
    acc.z = fmaf(pw, vv.z, acc.z);
    acc.w = fmaf(pw, vv.w, acc.w);
  }
  float* o = dout + b * Vv + c4 * 4;
  atomicAdd(o + 0, acc.x);
  atomicAdd(o + 1, acc.y);
  atomicAdd(o + 2, acc.z);
  atomicAdd(o + 3, acc.w);
}

// ---------------------------------------------------------------------------
extern "C" void kernel_launch(void* const* d_in, const int* in_sizes, int n_in,
                              void* d_out, int out_size, void* d_ws, size_t ws_size,
                              hipStream_t stream) {
  const float* q  = (const float*)d_in[0];
  const float* k  = (const float*)d_in[1];
  const float* v  = (const float*)d_in[2];
  const float* Wk = (const float*)d_in[3];
  const float* bk = (const float*)d_in[4];
  const float* Wq = (const float*)d_in[5];
  const float* bq = (const float*)d_in[6];
  const float* Wo = (const float*)d_in[7];

  float* out = (float*)d_out;
  char* ws = (char*)d_ws;
  float* hq = (float*)(ws + WS_HQ);
  uint16_t* wkb = (uint16_t*)(ws + WS_WKB);
  float* logits = (float*)(ws + WS_LOGIT);

  prep<<<dim3(384), dim3(256), 0, stream>>>(q, Wq, bq, bk, Wk, wkb, hq);
  fused_gemm_tanh_logit<<<dim3(Ss / 64, Bb), dim3(256), 0, stream>>>(k, wkb, hq, Wo, logits);
  softmax_zero<<<dim3(Bb), dim3(256), 0, stream>>>(logits, out);
  weighted_vsum<<<dim3(16, Bb), dim3(256), 0, stream>>>(v, out);
}